// Round 4
// baseline (593.556 us; speedup 1.0000x reference)
//
#include <hip/hip_runtime.h>
#include <hip/hip_bf16.h>
#include <stdint.h>

// out[2048,256] = x[2048,32768] @ W[32768,256],
// W[k,r] = U0[k&31, r] * U1[(k>>5)&31, r] * U2[k>>10, r]
//
// R4: fused kernel (W never materialized), SK=32 for occupancy.
// R3 post-mortem: kernel competes with the harness's 2x 1GiB poison fills
// (6.7 TB/s, ~318us of the timed window); its marginal cost is the
// non-overlapped tail (~71us), which is latency/BW-share-limited, not
// byte-limited. More resident waves = more outstanding loads = bigger HBM
// share + shorter tail.
//   - SK=32 -> KC=1024, NKI=16, grid = 32 mblk x 32 sk = 1024 blocks
//     = 3 blocks/CU at ~80 VGPR (24 waves/CU, was 16).
//   - i2 = k>>10 = sk exactly -> u2 is 2 regs, no half-loop.
//     i1 = (k>>5)&31 = 2*it+ks (it<16, no mask). i0 = quad*8+e (fixed).
//   - 8 waves = 1x8 column strips (64 rows x 32 cols, acc[4][2]).
//   - x prefetched 2 K-tiles ahead in regs; U1 prefetched 1 iter ahead.
//   - A: fp32 -> bf16 pack (round-half-up, same numerics as R0-R3) ->
//     XOR-swizzled LDS ds_write_b128.
//   - split-K fp32 atomicAdd epilogue; out zeroed by in-graph memset.
//     Atomic writes 33->67 MB: cheap vs doubled latency tolerance.

#define K_DIM 32768
#define R_DIM 256
#define BM 64
#define BK 64
#define SK 32
#define KC (K_DIM / SK)   // 1024 K per block
#define NKI (KC / BK)     // 16 iterations

typedef float f32x4 __attribute__((ext_vector_type(4)));
typedef short s16x8 __attribute__((ext_vector_type(8)));

// pack two fp32 -> two bf16 (round-half-up via +0x8000, then v_perm byte pick)
__device__ __forceinline__ uint32_t pack2_bf16(float a, float b) {
    uint32_t ua = __builtin_bit_cast(uint32_t, a) + 0x8000u;
    uint32_t ub = __builtin_bit_cast(uint32_t, b) + 0x8000u;
    return __builtin_amdgcn_perm(ub, ua, 0x07060302u);
}

__global__ __launch_bounds__(512, 6) void gemm_fused_kernel(
        const float* __restrict__ x, const float* __restrict__ U0,
        const float* __restrict__ U1, const float* __restrict__ U2,
        float* __restrict__ out) {
    __shared__ uint16_t As[BM * 64];   // 8 KB bf16, XOR-swizzled chunks

    const uint32_t bid  = blockIdx.x;
    const uint32_t sk   = bid & 31u;   // K split (also = i2)
    const uint32_t mblk = bid >> 5;    // x row block, 0..31

    const uint32_t tid  = threadIdx.x;
    const uint32_t lane = tid & 63u;
    const uint32_t wave = tid >> 6;    // 0..7: 32-column strip
    const uint32_t mloc = lane & 15u;
    const uint32_t quad = lane >> 4;

    // ---- B-fragment generation state (registers, loaded once) ----
    uint32_t rg[2];
    rg[0] = wave * 32u + mloc;
    rg[1] = rg[0] + 16u;
    float u0[2][8];   // U0[quad*8+e][rg[nt]] -- i0 iteration-invariant
#pragma unroll
    for (int nt = 0; nt < 2; ++nt)
#pragma unroll
        for (int e = 0; e < 8; ++e)
            u0[nt][e] = U0[(quad * 8u + (uint32_t)e) * 256u + rg[nt]];
    // i2 = sk exactly (it*64+ks*32+quad*8+e < 1024)
    const float u2c0 = U2[sk * 256u + rg[0]];
    const float u2c1 = U2[sk * 256u + rg[1]];

    // ---- A staging: thread owns row arow, k-chunk ac (8 fp32 = 32B) ----
    const uint32_t ac   = tid & 7u;
    const uint32_t arow = tid >> 3;                  // 0..63
    const uint32_t aoff = (ac ^ (arow & 7u)) * 8u;   // XOR swizzle (u16 units)
    const float* xg = x + (size_t)(mblk * BM + arow) * K_DIM + sk * KC + ac * 8u;

    const uint32_t aBase = mloc * 64u;               // + mt*1024 + sw

    // prologue: x tiles 0,1 and U1 for it=0 into regs
    f32x4 c0 = *(const f32x4*)(xg);
    f32x4 c1 = *(const f32x4*)(xg + 4);
    f32x4 n0 = *(const f32x4*)(xg + BK);
    f32x4 n1 = *(const f32x4*)(xg + BK + 4);
    f32x4 m0, m1;
    float u1c00 = U1[0u * 256u + rg[0]];   // i1(it=0,ks=0)=0
    float u1c01 = U1[0u * 256u + rg[1]];
    float u1c10 = U1[1u * 256u + rg[0]];   // i1(it=0,ks=1)=1
    float u1c11 = U1[1u * 256u + rg[1]];
    float u1n00, u1n01, u1n10, u1n11;

    f32x4 acc[4][2];
#pragma unroll
    for (int i = 0; i < 4; ++i)
#pragma unroll
        for (int j = 0; j < 2; ++j) acc[i][j] = (f32x4){0.f, 0.f, 0.f, 0.f};

    for (uint32_t it = 0; it < NKI; ++it) {
        // prefetch x tile it+2 (stays in flight across barriers + MFMA)
        if (it + 2u < NKI) {
            const float* g = xg + (it + 2u) * BK;
            m0 = *(const f32x4*)(g);
            m1 = *(const f32x4*)(g + 4);
        }
        // prefetch U1 scalars for it+1 (mask wraps harmlessly at it=15)
        {
            const uint32_t i1a = (2u * (it + 1u)) & 31u;
            const uint32_t i1b = (2u * (it + 1u) + 1u) & 31u;
            u1n00 = U1[i1a * 256u + rg[0]];
            u1n01 = U1[i1a * 256u + rg[1]];
            u1n10 = U1[i1b * 256u + rg[0]];
            u1n11 = U1[i1b * 256u + rg[1]];
        }

        // stage current K-tile: pack bf16, one swizzled ds_write_b128
        *(uint4*)(&As[arow * 64u + aoff]) = make_uint4(
            pack2_bf16(c0[0], c0[1]), pack2_bf16(c0[2], c0[3]),
            pack2_bf16(c1[0], c1[1]), pack2_bf16(c1[2], c1[3]));
        __syncthreads();

#pragma unroll
        for (int ks = 0; ks < 2; ++ks) {
            const uint32_t sw = (((uint32_t)ks * 4u + quad) ^ (mloc & 7u)) * 8u;
            s16x8 af[4];
#pragma unroll
            for (int mt = 0; mt < 4; ++mt)
                af[mt] = *(const s16x8*)(&As[aBase + (uint32_t)mt * 1024u + sw]);
#pragma unroll
            for (int nt = 0; nt < 2; ++nt) {
                const float u1s = ks ? (nt ? u1c11 : u1c10)
                                     : (nt ? u1c01 : u1c00);
                const float m = u1s * (nt ? u2c1 : u2c0);
                union { uint32_t u[4]; s16x8 v; } bb;
                bb.u[0] = pack2_bf16(u0[nt][0] * m, u0[nt][1] * m);
                bb.u[1] = pack2_bf16(u0[nt][2] * m, u0[nt][3] * m);
                bb.u[2] = pack2_bf16(u0[nt][4] * m, u0[nt][5] * m);
                bb.u[3] = pack2_bf16(u0[nt][6] * m, u0[nt][7] * m);
#pragma unroll
                for (int mt = 0; mt < 4; ++mt)
                    acc[mt][nt] = __builtin_amdgcn_mfma_f32_16x16x32_bf16(
                        af[mt], bb.v, acc[mt][nt], 0, 0, 0);
            }
        }
        __syncthreads();

        // shift pipelines
        c0 = n0; c1 = n1; n0 = m0; n1 = m1;
        u1c00 = u1n00; u1c01 = u1n01; u1c10 = u1n10; u1c11 = u1n11;
    }

    // epilogue: atomic accumulate split-K partial tile
    const uint32_t orow0 = mblk * BM + quad * 4u;
    const uint32_t ocol0 = wave * 32u + mloc;
#pragma unroll
    for (int mt = 0; mt < 4; ++mt) {
#pragma unroll
        for (int nt = 0; nt < 2; ++nt) {
            float* po = out + (size_t)(orow0 + (uint32_t)mt * 16u) * R_DIM +
                        ocol0 + (uint32_t)nt * 16u;
#pragma unroll
            for (int i = 0; i < 4; ++i)
                atomicAdd(po + (size_t)i * R_DIM, acc[mt][nt][i]);
        }
    }
}

extern "C" void kernel_launch(void* const* d_in, const int* in_sizes, int n_in,
                              void* d_out, int out_size, void* d_ws, size_t ws_size,
                              hipStream_t stream) {
    const float* x  = (const float*)d_in[0];
    const float* U0 = (const float*)d_in[1];
    const float* U1 = (const float*)d_in[2];
    const float* U2 = (const float*)d_in[3];
    float* out = (float*)d_out;
    (void)d_ws; (void)ws_size;

    // zero output (split-K atomic accumulation target)
    hipMemsetAsync(d_out, 0, (size_t)out_size * sizeof(float), stream);
    // fused W-gen + split-K MFMA GEMM, 1024 blocks x 512 threads (3 blocks/CU)
    gemm_fused_kernel<<<1024, 512, 0, stream>>>(x, U0, U1, U2, out);
}

// Round 5
// 388.787 us; speedup vs baseline: 1.5267x; 1.5267x over previous
//
#include <hip/hip_runtime.h>
#include <hip/hip_bf16.h>
#include <stdint.h>

// out[2048,256] = x[2048,32768] @ W[32768,256],
// W[k,r] = U0[k&31, r] * U1[(k>>5)&31, r] * U2[k>>10, r]
//
// R5: fused kernel (W never materialized) with ATOMIC-FREE split-K.
// R4 post-mortem: scattered fp32 atomicAdd cost ~32B memory-side RMW per
// 4B payload (553 MB WRITE + 211 MB extra FETCH for 67 MB of payload) and
// atomic-op throughput bound the kernel (3.1 TB/s, 337us). Fix: each block
// stores its 64x256 fp32 partial tile with plain coalesced stores into
// workspace ws[sk][row][col] (32 MB total), then a tiny reduce kernel sums
// the 16 partials per output (deterministic, coalesced, LLC-resident).
//
// Main loop = R3's proven config (best measured: 389us total):
//   - SK=16, BM=64 -> grid 32 mblk x 16 sk = 512 blocks = 2 blocks/CU
//     (16 waves/CU), 8 waves = 1x8 column strips (64r x 32c, acc[4][2]).
//   - B-frag synthesis in regs: k = sk*2048 + it*64 + ks*32 + quad*8 + e
//       i0 = quad*8+e (fixed/thread), i1 = (2*it+ks)&31 (prefetch 1 ahead),
//       i2 = sk*2 + (it>>4) (u2v[2][2] preload).
//   - x prefetched 2 K-tiles ahead in regs; bf16 round-half-up pack; LDS
//     XOR-swizzled ds_write_b128/ds_read_b128.

#define K_DIM 32768
#define R_DIM 256
#define BM 64
#define BK 64
#define SK 16
#define KC (K_DIM / SK)   // 2048 K per block
#define NKI (KC / BK)     // 32 iterations
#define OUT_ELEMS (2048u * 256u)   // 524288 floats, 2 MB

typedef float f32x4 __attribute__((ext_vector_type(4)));
typedef short s16x8 __attribute__((ext_vector_type(8)));

// pack two fp32 -> two bf16 (round-half-up via +0x8000, then v_perm byte pick)
__device__ __forceinline__ uint32_t pack2_bf16(float a, float b) {
    uint32_t ua = __builtin_bit_cast(uint32_t, a) + 0x8000u;
    uint32_t ub = __builtin_bit_cast(uint32_t, b) + 0x8000u;
    return __builtin_amdgcn_perm(ub, ua, 0x07060302u);
}

__global__ __launch_bounds__(512, 4) void gemm_fused_kernel(
        const float* __restrict__ x, const float* __restrict__ U0,
        const float* __restrict__ U1, const float* __restrict__ U2,
        float* __restrict__ ws) {
    __shared__ uint16_t As[BM * 64];   // 8 KB bf16, XOR-swizzled chunks

    const uint32_t bid  = blockIdx.x;
    const uint32_t sk   = bid & 15u;   // K split
    const uint32_t mblk = bid >> 4;    // x row block, 0..31

    const uint32_t tid  = threadIdx.x;
    const uint32_t lane = tid & 63u;
    const uint32_t wave = tid >> 6;    // 0..7: 32-column strip
    const uint32_t mloc = lane & 15u;
    const uint32_t quad = lane >> 4;

    // ---- B-fragment generation state (registers, loaded once) ----
    uint32_t rg[2];
    rg[0] = wave * 32u + mloc;
    rg[1] = rg[0] + 16u;
    float u0[2][8];   // U0[quad*8+e][rg[nt]] -- i0 iteration-invariant
#pragma unroll
    for (int nt = 0; nt < 2; ++nt)
#pragma unroll
        for (int e = 0; e < 8; ++e)
            u0[nt][e] = U0[(quad * 8u + (uint32_t)e) * 256u + rg[nt]];
    float u2v[2][2];  // U2[sk*2 + half][rg[nt]]
#pragma unroll
    for (int h = 0; h < 2; ++h)
#pragma unroll
        for (int nt = 0; nt < 2; ++nt)
            u2v[h][nt] = U2[(sk * 2u + (uint32_t)h) * 256u + rg[nt]];

    // ---- A staging: thread owns row arow, k-chunk ac (8 fp32 = 32B) ----
    const uint32_t ac   = tid & 7u;
    const uint32_t arow = tid >> 3;                  // 0..63
    const uint32_t aoff = (ac ^ (arow & 7u)) * 8u;   // XOR swizzle (u16 units)
    const float* xg = x + (size_t)(mblk * BM + arow) * K_DIM + sk * KC + ac * 8u;

    const uint32_t aBase = mloc * 64u;               // + mt*1024 + sw

    // prologue: x tiles 0,1 and U1 for it=0 into regs
    f32x4 c0 = *(const f32x4*)(xg);
    f32x4 c1 = *(const f32x4*)(xg + 4);
    f32x4 n0 = *(const f32x4*)(xg + BK);
    f32x4 n1 = *(const f32x4*)(xg + BK + 4);
    f32x4 m0, m1;
    float u1c00 = U1[0u * 256u + rg[0]];   // i1(it=0,ks=0)=0
    float u1c01 = U1[0u * 256u + rg[1]];
    float u1c10 = U1[1u * 256u + rg[0]];   // i1(it=0,ks=1)=1
    float u1c11 = U1[1u * 256u + rg[1]];
    float u1n00, u1n01, u1n10, u1n11;

    f32x4 acc[4][2];
#pragma unroll
    for (int i = 0; i < 4; ++i)
#pragma unroll
        for (int j = 0; j < 2; ++j) acc[i][j] = (f32x4){0.f, 0.f, 0.f, 0.f};

#pragma unroll
    for (int half = 0; half < 2; ++half) {
        const float u2c0 = u2v[half][0];
        const float u2c1 = u2v[half][1];

#pragma unroll
        for (int itl = 0; itl < 16; ++itl) {
            const uint32_t it = (uint32_t)half * 16u + (uint32_t)itl;

            // prefetch x tile it+2 (stays in flight across barriers + MFMA)
            if (it + 2u < NKI) {
                const float* g = xg + (it + 2u) * BK;
                m0 = *(const f32x4*)(g);
                m1 = *(const f32x4*)(g + 4);
            }
            // prefetch U1 scalars for it+1 (mask wraps harmlessly at it=31)
            {
                const uint32_t i1a = (2u * (it + 1u)) & 31u;
                const uint32_t i1b = (2u * (it + 1u) + 1u) & 31u;
                u1n00 = U1[i1a * 256u + rg[0]];
                u1n01 = U1[i1a * 256u + rg[1]];
                u1n10 = U1[i1b * 256u + rg[0]];
                u1n11 = U1[i1b * 256u + rg[1]];
            }

            // stage current K-tile: pack bf16, one swizzled ds_write_b128
            *(uint4*)(&As[arow * 64u + aoff]) = make_uint4(
                pack2_bf16(c0[0], c0[1]), pack2_bf16(c0[2], c0[3]),
                pack2_bf16(c1[0], c1[1]), pack2_bf16(c1[2], c1[3]));
            __syncthreads();

#pragma unroll
            for (int ks = 0; ks < 2; ++ks) {
                const uint32_t sw = (((uint32_t)ks * 4u + quad) ^ (mloc & 7u)) * 8u;
                s16x8 af[4];
#pragma unroll
                for (int mt = 0; mt < 4; ++mt)
                    af[mt] = *(const s16x8*)(&As[aBase + (uint32_t)mt * 1024u + sw]);
#pragma unroll
                for (int nt = 0; nt < 2; ++nt) {
                    const float u1s = ks ? (nt ? u1c11 : u1c10)
                                         : (nt ? u1c01 : u1c00);
                    const float m = u1s * (nt ? u2c1 : u2c0);
                    union { uint32_t u[4]; s16x8 v; } bb;
                    bb.u[0] = pack2_bf16(u0[nt][0] * m, u0[nt][1] * m);
                    bb.u[1] = pack2_bf16(u0[nt][2] * m, u0[nt][3] * m);
                    bb.u[2] = pack2_bf16(u0[nt][4] * m, u0[nt][5] * m);
                    bb.u[3] = pack2_bf16(u0[nt][6] * m, u0[nt][7] * m);
#pragma unroll
                    for (int mt = 0; mt < 4; ++mt)
                        acc[mt][nt] = __builtin_amdgcn_mfma_f32_16x16x32_bf16(
                            af[mt], bb.v, acc[mt][nt], 0, 0, 0);
                }
            }
            __syncthreads();

            // shift pipelines
            c0 = n0; c1 = n1; n0 = m0; n1 = m1;
            u1c00 = u1n00; u1c01 = u1n01; u1c10 = u1n10; u1c11 = u1n11;
        }
    }

    // epilogue: plain coalesced stores of the partial tile (NO atomics).
    // ws layout: [sk][global_row][col] fp32 -> sk*524288 + row*256 + col
    const uint32_t orow0 = mblk * BM + quad * 4u;
    const uint32_t ocol0 = wave * 32u + mloc;
    float* wsk = ws + (size_t)sk * OUT_ELEMS;
#pragma unroll
    for (int mt = 0; mt < 4; ++mt) {
#pragma unroll
        for (int nt = 0; nt < 2; ++nt) {
            float* po = wsk + (size_t)(orow0 + (uint32_t)mt * 16u) * R_DIM +
                        ocol0 + (uint32_t)nt * 16u;
#pragma unroll
            for (int i = 0; i < 4; ++i)
                po[(size_t)i * R_DIM] = acc[mt][nt][i];
        }
    }
}

// sum the 16 split-K partials; deterministic order, fully coalesced.
__global__ __launch_bounds__(256) void reduce_kernel(
        const float* __restrict__ ws, float* __restrict__ out) {
    const uint32_t f = (blockIdx.x * 256u + threadIdx.x) * 4u;  // grid covers 2MB
    f32x4 s = *(const f32x4*)(ws + f);
#pragma unroll
    for (int sk = 1; sk < SK; ++sk)
        s += *(const f32x4*)(ws + (size_t)sk * OUT_ELEMS + f);
    *(f32x4*)(out + f) = s;
}

extern "C" void kernel_launch(void* const* d_in, const int* in_sizes, int n_in,
                              void* d_out, int out_size, void* d_ws, size_t ws_size,
                              hipStream_t stream) {
    const float* x  = (const float*)d_in[0];
    const float* U0 = (const float*)d_in[1];
    const float* U1 = (const float*)d_in[2];
    const float* U2 = (const float*)d_in[3];
    float* out = (float*)d_out;
    float* ws  = (float*)d_ws;   // needs SK * 2 MB = 32 MB

    // fused W-gen + split-K MFMA GEMM -> fp32 partials in ws (no atomics)
    gemm_fused_kernel<<<512, 512, 0, stream>>>(x, U0, U1, U2, ws);
    // deterministic split-K reduction: 524288 floats / (256 thr * 4) = 512 blocks
    reduce_kernel<<<512, 256, 0, stream>>>(ws, out);
}